// Round 1
// baseline (635.438 us; speedup 1.0000x reference)
//
#include <hip/hip_runtime.h>

#define D 128
#define PCOLS 640   // [hW0 | hW1 | Q | K | V]

// ---------------- CSR build ----------------

__global__ void hist_k(const int* __restrict__ dst, int* __restrict__ cnt, int E) {
  int e = blockIdx.x * blockDim.x + threadIdx.x;
  if (e < E) atomicAdd(&cnt[dst[e]], 1);
}

__global__ void exscan_k(int* __restrict__ cnt_cursor, int* __restrict__ rp, int n) {
  __shared__ int buf[2][1024];
  __shared__ int carry_s;
  int tid = threadIdx.x;
  if (tid == 0) carry_s = 0;
  __syncthreads();
  for (int base = 0; base < n; base += 1024) {
    int idx = base + tid;
    int v = (idx < n) ? cnt_cursor[idx] : 0;
    int cur = 0;
    buf[0][tid] = v;
    __syncthreads();
    for (int ofs = 1; ofs < 1024; ofs <<= 1) {
      int nxt = cur ^ 1;
      int val = buf[cur][tid];
      if (tid >= ofs) val += buf[cur][tid - ofs];
      buf[nxt][tid] = val;
      cur = nxt;
      __syncthreads();
    }
    int inc = buf[cur][tid];
    int carry = carry_s;          // read old carry (sync below orders vs update)
    int ex = inc - v + carry;
    if (idx < n) { rp[idx] = ex; cnt_cursor[idx] = ex; }
    __syncthreads();
    if (tid == 1023) carry_s = carry + buf[cur][1023];
    __syncthreads();
  }
  if (tid == 0) rp[n] = carry_s;
}

__global__ void fill_k(const int* __restrict__ src, const int* __restrict__ dst,
                       int* __restrict__ cursor, int* __restrict__ srcs, int E) {
  int e = blockIdx.x * blockDim.x + threadIdx.x;
  if (e < E) {
    int pos = atomicAdd(&cursor[dst[e]], 1);
    srcs[pos] = src[e];
  }
}

// ---------------- fused 5-output GEMM: P[N,640] = h[N,128] @ [W0|W1|Wq|Wk|Wv] ----------------

__global__ __launch_bounds__(256) void gemm5_k(
    const float* __restrict__ A,
    const float* __restrict__ W0, const float* __restrict__ W1,
    const float* __restrict__ W2, const float* __restrict__ W3,
    const float* __restrict__ W4,
    float* __restrict__ P, int N) {
  __shared__ float Ast[128][68];   // A transposed, padded stride (68*4=272B, 16B-aligned rows)
  __shared__ float Bs[128][64];
  const int tid = threadIdx.x;
  const int by = blockIdx.y;                 // 0..9 (two 64-col blocks per weight)
  const int wsel = by >> 1;
  const int loff = (by & 1) * 64;
  const float* __restrict__ W =
      (wsel == 0) ? W0 : (wsel == 1) ? W1 : (wsel == 2) ? W2 : (wsel == 3) ? W3 : W4;
  const int row0 = blockIdx.x * 64;

  // stage A (transposed into Ast[k][r])
  {
    int kq = tid & 31;          // float4 index along K
    int r0 = tid >> 5;          // 0..7
    for (int rr = r0; rr < 64; rr += 8) {
      int row = row0 + rr;
      float4 v = make_float4(0.f, 0.f, 0.f, 0.f);
      if (row < N) v = *(const float4*)&A[row * D + kq * 4];
      Ast[kq * 4 + 0][rr] = v.x;
      Ast[kq * 4 + 1][rr] = v.y;
      Ast[kq * 4 + 2][rr] = v.z;
      Ast[kq * 4 + 3][rr] = v.w;
    }
    // stage B: Bs[k][c] = W[k][loff + c]
    int c4 = tid & 15;
    int k0 = tid >> 4;          // 0..15
    for (int kk = k0; kk < 128; kk += 16) {
      *(float4*)&Bs[kk][c4 * 4] = *(const float4*)&W[kk * D + loff + c4 * 4];
    }
  }
  __syncthreads();

  const int tx = tid & 15, ty = tid >> 4;
  const int ry = ty * 4, cx = tx * 4;
  float acc[4][4] = {};
#pragma unroll 8
  for (int k = 0; k < 128; ++k) {
    float4 a = *(const float4*)&Ast[k][ry];
    float4 b = *(const float4*)&Bs[k][cx];
    acc[0][0] += a.x * b.x; acc[0][1] += a.x * b.y; acc[0][2] += a.x * b.z; acc[0][3] += a.x * b.w;
    acc[1][0] += a.y * b.x; acc[1][1] += a.y * b.y; acc[1][2] += a.y * b.z; acc[1][3] += a.y * b.w;
    acc[2][0] += a.z * b.x; acc[2][1] += a.z * b.y; acc[2][2] += a.z * b.z; acc[2][3] += a.z * b.w;
    acc[3][0] += a.w * b.x; acc[3][1] += a.w * b.y; acc[3][2] += a.w * b.z; acc[3][3] += a.w * b.w;
  }

  const int colbase = by * 64 + cx;
#pragma unroll
  for (int ii = 0; ii < 4; ++ii) {
    int row = row0 + ry + ii;
    if (row < N) {
      float4 o = make_float4(acc[ii][0], acc[ii][1], acc[ii][2], acc[ii][3]);
      *(float4*)&P[row * PCOLS + colbase] = o;
    }
  }
}

// ---------------- fused per-node output: one wave per destination node ----------------
// out[i] = P0[i] + sum_{CSR1(i)} P1[j]  -  sum_{CSR2(i)} (Q[i]·K[j]) * V[j]

__device__ __forceinline__ float wave_reduce_sum(float v) {
  v += __shfl_xor(v, 32);
  v += __shfl_xor(v, 16);
  v += __shfl_xor(v, 8);
  v += __shfl_xor(v, 4);
  v += __shfl_xor(v, 2);
  v += __shfl_xor(v, 1);
  return v;
}

__global__ __launch_bounds__(256) void out_k(
    const float* __restrict__ P,
    const int* __restrict__ rp1, const int* __restrict__ srcs1,
    const int* __restrict__ rp2, const int* __restrict__ srcs2,
    float* __restrict__ hout, int N) {
  int gw = (int)((blockIdx.x * blockDim.x + threadIdx.x) >> 6);
  int l = threadIdx.x & 63;
  if (gw >= N) return;
  const int i = gw;
  const int bi = i * PCOLS;
  const int f = 2 * l;

  float2 acc = *(const float2*)&P[bi + 0 + f];      // hW0 row
  float2 q   = *(const float2*)&P[bi + 256 + f];    // Q row
  const float qx = q.x, qy = q.y;

  // --- TAGConv aggregation: + sum P1[j] ---
  int e = rp1[i], end = rp1[i + 1];
  for (; e + 4 <= end; e += 4) {
    int j0 = srcs1[e + 0] * PCOLS;
    int j1 = srcs1[e + 1] * PCOLS;
    int j2 = srcs1[e + 2] * PCOLS;
    int j3 = srcs1[e + 3] * PCOLS;
    float2 a0 = *(const float2*)&P[j0 + 128 + f];
    float2 a1 = *(const float2*)&P[j1 + 128 + f];
    float2 a2 = *(const float2*)&P[j2 + 128 + f];
    float2 a3 = *(const float2*)&P[j3 + 128 + f];
    acc.x += (a0.x + a1.x) + (a2.x + a3.x);
    acc.y += (a0.y + a1.y) + (a2.y + a3.y);
  }
  for (; e < end; ++e) {
    int j = srcs1[e] * PCOLS;
    float2 a = *(const float2*)&P[j + 128 + f];
    acc.x += a.x; acc.y += a.y;
  }

  // --- attention: - sum (q·k_j) v_j ---
  e = rp2[i]; end = rp2[i + 1];
  for (; e + 2 <= end; e += 2) {
    int j0 = srcs2[e + 0] * PCOLS;
    int j1 = srcs2[e + 1] * PCOLS;
    float2 k0 = *(const float2*)&P[j0 + 384 + f];
    float2 v0 = *(const float2*)&P[j0 + 512 + f];
    float2 k1 = *(const float2*)&P[j1 + 384 + f];
    float2 v1 = *(const float2*)&P[j1 + 512 + f];
    float d0 = wave_reduce_sum(qx * k0.x + qy * k0.y);
    float d1 = wave_reduce_sum(qx * k1.x + qy * k1.y);
    acc.x -= d0 * v0.x; acc.y -= d0 * v0.y;
    acc.x -= d1 * v1.x; acc.y -= d1 * v1.y;
  }
  for (; e < end; ++e) {
    int j = srcs2[e] * PCOLS;
    float2 kk = *(const float2*)&P[j + 384 + f];
    float2 vv = *(const float2*)&P[j + 512 + f];
    float d = wave_reduce_sum(qx * kk.x + qy * kk.y);
    acc.x -= d * vv.x; acc.y -= d * vv.y;
  }

  *(float2*)&hout[i * D + f] = acc;
}

// ---------------- host ----------------

extern "C" void kernel_launch(void* const* d_in, const int* in_sizes, int n_in,
                              void* d_out, int out_size, void* d_ws, size_t ws_size,
                              hipStream_t stream) {
  const float* x  = (const float*)d_in[0];
  const int* ei1  = (const int*)d_in[1];
  const int* ei2  = (const int*)d_in[2];
  const float* W0 = (const float*)d_in[3];
  const float* W1 = (const float*)d_in[4];
  const float* Wq = (const float*)d_in[5];
  const float* Wk = (const float*)d_in[6];
  const float* Wv = (const float*)d_in[7];

  const int N  = in_sizes[0] / D;
  const int E1 = in_sizes[1] / 2;
  const int E2 = in_sizes[2] / 2;
  const int* src1 = ei1;
  const int* dst1 = ei1 + E1;
  const int* src2 = ei2;
  const int* dst2 = ei2 + E2;

  // workspace layout (floats first for alignment)
  float* P  = (float*)d_ws;                       // N*640
  float* hA = P + (size_t)N * PCOLS;              // N*128
  float* hB = hA + (size_t)N * D;                 // N*128
  int* rp1  = (int*)(hB + (size_t)N * D);         // N+1
  int* rp2  = rp1 + (N + 1);                      // N+1
  int* cur1 = rp2 + (N + 1);                      // N
  int* cur2 = cur1 + N;                           // N
  int* srcs1 = cur2 + N;                          // E1
  int* srcs2 = srcs1 + E1;                        // E2

  size_t needed = ((size_t)N * PCOLS + 2ull * N * D) * 4ull +
                  ((size_t)2 * (N + 1) + 2ull * N + E1 + E2) * 4ull;
  if (ws_size < needed) return;

  float* out = (float*)d_out;

  // CSR build (once per launch; edge lists are reused by all 5 steps)
  hipMemsetAsync(cur1, 0, (size_t)N * sizeof(int), stream);
  hipMemsetAsync(cur2, 0, (size_t)N * sizeof(int), stream);
  int eb1 = (E1 + 255) / 256, eb2 = (E2 + 255) / 256;
  hist_k<<<eb1, 256, 0, stream>>>(dst1, cur1, E1);
  hist_k<<<eb2, 256, 0, stream>>>(dst2, cur2, E2);
  exscan_k<<<1, 1024, 0, stream>>>(cur1, rp1, N);
  exscan_k<<<1, 1024, 0, stream>>>(cur2, rp2, N);
  fill_k<<<eb1, 256, 0, stream>>>(src1, dst1, cur1, srcs1, E1);
  fill_k<<<eb2, 256, 0, stream>>>(src2, dst2, cur2, srcs2, E2);

  dim3 ggrid((N + 63) / 64, 10);
  int oblocks = (N * 64 + 255) / 256;

  const float* hcur = x;
  for (int s = 0; s < 5; ++s) {
    gemm5_k<<<ggrid, 256, 0, stream>>>(hcur, W0, W1, Wq, Wk, Wv, P, N);
    float* hnext = (s == 4) ? out : ((s & 1) ? hB : hA);
    out_k<<<oblocks, 256, 0, stream>>>(P, rp1, srcs1, rp2, srcs2, hnext, N);
    hcur = hnext;
  }
}

// Round 2
// 548.038 us; speedup vs baseline: 1.1595x; 1.1595x over previous
//
#include <hip/hip_runtime.h>

#define D 128

// ---------------- CSR build ----------------

__global__ void hist_k(const int* __restrict__ dst, int* __restrict__ cnt, int E) {
  int e = blockIdx.x * blockDim.x + threadIdx.x;
  if (e < E) atomicAdd(&cnt[dst[e]], 1);
}

__device__ void exscan_dev(int* cnt_cursor, int* rp, int n) {
  __shared__ int buf[2][1024];
  __shared__ int carry_s;
  int tid = threadIdx.x;
  if (tid == 0) carry_s = 0;
  __syncthreads();
  for (int base = 0; base < n; base += 1024) {
    int idx = base + tid;
    int v = (idx < n) ? cnt_cursor[idx] : 0;
    int cur = 0;
    buf[0][tid] = v;
    __syncthreads();
    for (int ofs = 1; ofs < 1024; ofs <<= 1) {
      int nxt = cur ^ 1;
      int val = buf[cur][tid];
      if (tid >= ofs) val += buf[cur][tid - ofs];
      buf[nxt][tid] = val;
      cur = nxt;
      __syncthreads();
    }
    int inc = buf[cur][tid];
    int carry = carry_s;
    int ex = inc - v + carry;
    if (idx < n) { rp[idx] = ex; cnt_cursor[idx] = ex; }
    __syncthreads();
    if (tid == 1023) carry_s = carry + buf[cur][1023];
    __syncthreads();
  }
  if (tid == 0) rp[n] = carry_s;
}

__global__ void exscan2_k(int* c1, int* r1, int* c2, int* r2, int n) {
  if (blockIdx.x == 0) exscan_dev(c1, r1, n);
  else exscan_dev(c2, r2, n);
}

__global__ void fill_k(const int* __restrict__ src, const int* __restrict__ dst,
                       int* __restrict__ cursor, int* __restrict__ srcs, int E) {
  int e = blockIdx.x * blockDim.x + threadIdx.x;
  if (e < E) {
    int pos = atomicAdd(&cursor[dst[e]], 1);
    srcs[pos] = src[e];
  }
}

// ---------------- weight precompute ----------------
// M = Wq @ Wk^T   (alpha_ij = h_i M h_j^T)
__global__ __launch_bounds__(128) void mk_M(const float* __restrict__ Wq,
                                            const float* __restrict__ Wk,
                                            float* __restrict__ M) {
  int r = blockIdx.x, c = threadIdx.x;
  float acc = 0.f;
  for (int d = 0; d < D; ++d) acc += Wq[r * D + d] * Wk[c * D + d];
  M[r * D + c] = acc;
}

// Wcat = [W0 ; W1 ; -Wv]  (384 x 128)
__global__ __launch_bounds__(256) void mk_Wcat(const float* __restrict__ W0,
                                               const float* __restrict__ W1,
                                               const float* __restrict__ Wv,
                                               float* __restrict__ Wc) {
  int idx = blockIdx.x * blockDim.x + threadIdx.x;
  if (idx >= 384 * D) return;
  int r = idx >> 7, c = idx & 127;
  float v;
  if (r < 128) v = W0[r * D + c];
  else if (r < 256) v = W1[(r - 128) * D + c];
  else v = -Wv[(r - 256) * D + c];
  Wc[idx] = v;
}

// WM = Wcat @ M  (384 x 128)
__global__ __launch_bounds__(128) void mk_WM(const float* __restrict__ Wc,
                                             const float* __restrict__ M,
                                             float* __restrict__ WM) {
  int r = blockIdx.x, c = threadIdx.x;
  float acc = 0.f;
  for (int k = 0; k < D; ++k) acc += Wc[r * D + k] * M[k * D + c];
  WM[r * D + c] = acc;
}

// ---------------- gather/aggregate: one wave per node ----------------
// agg1_i = sum_{CSR1(i)} h_j ;  aggA_i = sum_{CSR2(i)} (Qt_i . h_j) h_j
__device__ __forceinline__ float wave_reduce_sum(float v) {
  v += __shfl_xor(v, 32);
  v += __shfl_xor(v, 16);
  v += __shfl_xor(v, 8);
  v += __shfl_xor(v, 4);
  v += __shfl_xor(v, 2);
  v += __shfl_xor(v, 1);
  return v;
}

__global__ __launch_bounds__(256) void agg_k(
    const float* __restrict__ h, int ldh,
    const float* __restrict__ qt, int ldqt,
    const int* __restrict__ rp1, const int* __restrict__ s1,
    const int* __restrict__ rp2, const int* __restrict__ s2,
    float* __restrict__ G, int N) {
  int gw = (int)((blockIdx.x * blockDim.x + threadIdx.x) >> 6);
  if (gw >= N) return;
  const int i = __builtin_amdgcn_readfirstlane(gw);
  const int l = threadIdx.x & 63;
  const int f = 2 * l;

  float2 q = *(const float2*)&qt[(size_t)i * ldqt + f];
  float2 a1 = make_float2(0.f, 0.f);
  float2 a2 = make_float2(0.f, 0.f);

  // TAGConv neighbor sum
  int e = rp1[i], end = rp1[i + 1];
  for (; e + 8 <= end; e += 8) {
    float2 v[8];
#pragma unroll
    for (int u = 0; u < 8; ++u) {
      int j = s1[e + u];
      v[u] = *(const float2*)&h[(size_t)j * ldh + f];
    }
#pragma unroll
    for (int u = 0; u < 8; ++u) { a1.x += v[u].x; a1.y += v[u].y; }
  }
  for (; e < end; ++e) {
    int j = s1[e];
    float2 v = *(const float2*)&h[(size_t)j * ldh + f];
    a1.x += v.x; a1.y += v.y;
  }

  // attention aggregate (single gather serves dot + accumulation)
  e = rp2[i]; end = rp2[i + 1];
  for (; e + 4 <= end; e += 4) {
    float2 v[4]; float p[4];
#pragma unroll
    for (int u = 0; u < 4; ++u) {
      int j = s2[e + u];
      v[u] = *(const float2*)&h[(size_t)j * ldh + f];
    }
#pragma unroll
    for (int u = 0; u < 4; ++u) p[u] = q.x * v[u].x + q.y * v[u].y;
#pragma unroll
    for (int ofs = 32; ofs >= 1; ofs >>= 1) {
#pragma unroll
      for (int u = 0; u < 4; ++u) p[u] += __shfl_xor(p[u], ofs);
    }
#pragma unroll
    for (int u = 0; u < 4; ++u) {
      a2.x += p[u] * v[u].x; a2.y += p[u] * v[u].y;
    }
  }
  for (; e < end; ++e) {
    int j = s2[e];
    float2 v = *(const float2*)&h[(size_t)j * ldh + f];
    float p = wave_reduce_sum(q.x * v.x + q.y * v.y);
    a2.x += p * v.x; a2.y += p * v.y;
  }

  *(float2*)&G[(size_t)i * 256 + f] = a1;
  *(float2*)&G[(size_t)i * 256 + 128 + f] = a2;
}

// ---------------- GEMM: C[:, by-block] += segs(A) @ B ----------------
// W path (by < nby_w): B = Bw (nseg*128 x 128), outcol = by*64
// Q path (by >= nby_w): B = Bm, outcol = 128 + (by-nby_w)*64
__global__ __launch_bounds__(256) void gemm_k(
    const float* __restrict__ A0, int lda0,
    const float* __restrict__ A1, const float* __restrict__ A2,
    int nseg,
    const float* __restrict__ Bw, const float* __restrict__ Bm, int nby_w,
    float* __restrict__ C, int ldC, int N) {
  __shared__ float Ast[128][68];
  __shared__ float Bs[128][64];
  const int tid = threadIdx.x;
  const int by = blockIdx.y;
  const float* __restrict__ B = (by < nby_w) ? Bw : Bm;
  const int bcol = (by < nby_w) ? by * 64 : (by - nby_w) * 64;
  const int outcol = (by < nby_w) ? by * 64 : 128 + (by - nby_w) * 64;
  const int row0 = blockIdx.x * 64;

  const int tx = tid & 15, ty = tid >> 4;
  const int ry = ty * 4, cx = tx * 4;
  float acc[4][4] = {};

  for (int seg = 0; seg < nseg; ++seg) {
    const float* __restrict__ As = (seg == 0) ? A0 : (seg == 1) ? A1 : A2;
    const int lda = (seg == 0) ? lda0 : 256;
    const float* __restrict__ Bseg = B + seg * 128 * D;

    {
      int kq = tid & 31, r0 = tid >> 5;
      for (int rr = r0; rr < 64; rr += 8) {
        int row = row0 + rr;
        float4 v = make_float4(0.f, 0.f, 0.f, 0.f);
        if (row < N) v = *(const float4*)&As[(size_t)row * lda + kq * 4];
        Ast[kq * 4 + 0][rr] = v.x;
        Ast[kq * 4 + 1][rr] = v.y;
        Ast[kq * 4 + 2][rr] = v.z;
        Ast[kq * 4 + 3][rr] = v.w;
      }
      int c4 = tid & 15, k0 = tid >> 4;
      for (int kk = k0; kk < 128; kk += 16)
        *(float4*)&Bs[kk][c4 * 4] = *(const float4*)&Bseg[kk * D + bcol + c4 * 4];
    }
    __syncthreads();

#pragma unroll 8
    for (int k = 0; k < 128; ++k) {
      float4 a = *(const float4*)&Ast[k][ry];
      float4 b = *(const float4*)&Bs[k][cx];
      acc[0][0] += a.x * b.x; acc[0][1] += a.x * b.y; acc[0][2] += a.x * b.z; acc[0][3] += a.x * b.w;
      acc[1][0] += a.y * b.x; acc[1][1] += a.y * b.y; acc[1][2] += a.y * b.z; acc[1][3] += a.y * b.w;
      acc[2][0] += a.z * b.x; acc[2][1] += a.z * b.y; acc[2][2] += a.z * b.z; acc[2][3] += a.z * b.w;
      acc[3][0] += a.w * b.x; acc[3][1] += a.w * b.y; acc[3][2] += a.w * b.z; acc[3][3] += a.w * b.w;
    }
    __syncthreads();
  }

#pragma unroll
  for (int ii = 0; ii < 4; ++ii) {
    int row = row0 + ry + ii;
    if (row < N) {
      float4 o = make_float4(acc[ii][0], acc[ii][1], acc[ii][2], acc[ii][3]);
      *(float4*)&C[(size_t)row * ldC + outcol + cx] = o;
    }
  }
}

// ---------------- host ----------------

extern "C" void kernel_launch(void* const* d_in, const int* in_sizes, int n_in,
                              void* d_out, int out_size, void* d_ws, size_t ws_size,
                              hipStream_t stream) {
  const float* x  = (const float*)d_in[0];
  const int* ei1  = (const int*)d_in[1];
  const int* ei2  = (const int*)d_in[2];
  const float* W0 = (const float*)d_in[3];
  const float* W1 = (const float*)d_in[4];
  const float* Wq = (const float*)d_in[5];
  const float* Wk = (const float*)d_in[6];
  const float* Wv = (const float*)d_in[7];

  const int N  = in_sizes[0] / D;
  const int E1 = in_sizes[1] / 2;
  const int E2 = in_sizes[2] / 2;
  const int* src1 = ei1;
  const int* dst1 = ei1 + E1;
  const int* src2 = ei2;
  const int* dst2 = ei2 + E2;

  float* H2A = (float*)d_ws;                 // N x 256  [h | Qt]
  float* H2B = H2A + (size_t)N * 256;        // N x 256
  float* G   = H2B + (size_t)N * 256;        // N x 256  [agg1 | aggA]
  float* M   = G   + (size_t)N * 256;        // 128x128
  float* Wc  = M + 128 * D;                  // 384x128
  float* WM  = Wc + 384 * D;                 // 384x128
  int* rp1   = (int*)(WM + 384 * D);         // N+1
  int* rp2   = rp1 + (N + 1);                // N+1
  int* cur1  = rp2 + (N + 1);                // N
  int* cur2  = cur1 + N;                     // N
  int* srcs1 = cur2 + N;                     // E1
  int* srcs2 = srcs1 + E1;                   // E2

  size_t needed = ((size_t)N * 768 + 128 * D + 2 * 384 * D) * 4ull +
                  ((size_t)2 * (N + 1) + 2ull * N + E1 + E2) * 4ull;
  if (ws_size < needed) return;

  float* out = (float*)d_out;

  // weight precompute
  mk_M<<<128, 128, 0, stream>>>(Wq, Wk, M);
  mk_Wcat<<<(384 * D + 255) / 256, 256, 0, stream>>>(W0, W1, Wv, Wc);
  mk_WM<<<384, 128, 0, stream>>>(Wc, M, WM);

  // CSR build
  hipMemsetAsync(cur1, 0, (size_t)N * sizeof(int), stream);
  hipMemsetAsync(cur2, 0, (size_t)N * sizeof(int), stream);
  int eb1 = (E1 + 255) / 256, eb2 = (E2 + 255) / 256;
  hist_k<<<eb1, 256, 0, stream>>>(dst1, cur1, E1);
  hist_k<<<eb2, 256, 0, stream>>>(dst2, cur2, E2);
  exscan2_k<<<2, 1024, 0, stream>>>(cur1, rp1, cur2, rp2, N);
  fill_k<<<eb1, 256, 0, stream>>>(src1, dst1, cur1, srcs1, E1);
  fill_k<<<eb2, 256, 0, stream>>>(src2, dst2, cur2, srcs2, E2);

  const int gx = (N + 63) / 64;
  const int ablocks = (N * 64 + 255) / 256;

  // Qt0 = x @ M  -> H2B cols 128..255
  gemm_k<<<dim3(gx, 2), 256, 0, stream>>>(x, D, nullptr, nullptr, 1,
                                          nullptr, M, 0, H2B, 256, N);

  for (int s = 0; s < 5; ++s) {
    const float* hsrc;
    int ldh;
    if (s == 0)      { hsrc = x;   ldh = D; }
    else if (s & 1)  { hsrc = H2A; ldh = 256; }   // s1,s3 read H2A (written s0,s2)
    else             { hsrc = H2B; ldh = 256; }   // s2,s4 read H2B (written s1,s3)
    const float* qtsrc = (s == 0) ? (H2B + 128) : (hsrc + 128);

    agg_k<<<ablocks, 256, 0, stream>>>(hsrc, ldh, qtsrc, 256,
                                       rp1, srcs1, rp2, srcs2, G, N);

    if (s == 4) {
      gemm_k<<<dim3(gx, 2), 256, 0, stream>>>(hsrc, ldh, G, G + 128, 3,
                                              Wc, WM, 2, out, D, N);
    } else {
      float* Cdst = (s & 1) ? H2B : H2A;
      gemm_k<<<dim3(gx, 4), 256, 0, stream>>>(hsrc, ldh, G, G + 128, 3,
                                              Wc, WM, 2, Cdst, 256, N);
    }
  }
}